// Round 6
// baseline (163.248 us; speedup 1.0000x reference)
//
#include <hip/hip_runtime.h>

#define N_NODES 100000
#define N_EDGES 600000
#define DIM 128

#define N4 (N_NODES / 4)          // 25000 int4 chunks of the count array
#define SCAN_BLOCKS ((N_NODES + 1023) / 1024)   // 98

typedef __attribute__((ext_vector_type(8))) short bf16x8;
typedef __attribute__((ext_vector_type(4))) float f32x4;

__device__ __forceinline__ void fma4(float4& acc, float s, const float4 w) {
    acc.x = fmaf(s, w.x, acc.x);
    acc.y = fmaf(s, w.y, acc.y);
    acc.z = fmaf(s, w.z, acc.z);
    acc.w = fmaf(s, w.w, acc.w);
}

__device__ __forceinline__ unsigned short f2bf(float f) {
    union { float f; unsigned int u; } v; v.f = f;
    unsigned int r = v.u + 0x7fffu + ((v.u >> 16) & 1u);   // RNE
    return (unsigned short)(r >> 16);
}

__device__ __forceinline__ float bf2f(unsigned short u) {
    union { unsigned int i; float f; } v;
    v.i = ((unsigned int)u) << 16;
    return v.f;
}

// CSR build step 1: degree histogram (cnt must be zeroed before)
__global__ __launch_bounds__(256) void hist_kernel(
    const int* __restrict__ rows, int* __restrict__ cnt)
{
    int e = blockIdx.x * 256 + threadIdx.x;
    if (e >= N_EDGES) return;
    atomicAdd(&cnt[rows[e]], 1);
}

// scan level 1
__global__ __launch_bounds__(256) void scan1_kernel(
    const int* __restrict__ cnt, int* __restrict__ off, int* __restrict__ bsum)
{
    __shared__ int s[256];
    int t = threadIdx.x;
    int b = blockIdx.x;
    int i4 = b * 256 + t;
    int4 c = {0, 0, 0, 0};
    if (i4 < N4) c = ((const int4*)cnt)[i4];
    int tsum = c.x + c.y + c.z + c.w;
    s[t] = tsum;
    __syncthreads();
    for (int d = 1; d < 256; d <<= 1) {
        int v = (t >= d) ? s[t - d] : 0;
        __syncthreads();
        s[t] += v;
        __syncthreads();
    }
    int texcl = s[t] - tsum;
    if (t == 255) bsum[b] = s[255];
    if (i4 < N4) {
        int4 o;
        o.x = texcl;
        o.y = o.x + c.x;
        o.z = o.y + c.y;
        o.w = o.z + c.z;
        ((int4*)off)[i4] = o;
    }
}

// scan level 2+3
__global__ __launch_bounds__(256) void scan3_kernel(
    const int* __restrict__ bsum, int* __restrict__ off, int* __restrict__ cur)
{
    __shared__ int s[256];
    int t = threadIdx.x;
    int b = blockIdx.x;
    s[t] = (t < b && t < SCAN_BLOCKS) ? bsum[t] : 0;
    __syncthreads();
    for (int d = 1; d < 256; d <<= 1) {
        int v = (t >= d) ? s[t - d] : 0;
        __syncthreads();
        s[t] += v;
        __syncthreads();
    }
    int base = s[255];
    int i4 = b * 256 + t;
    if (i4 < N4) {
        int4 o = ((const int4*)off)[i4];
        o.x += base; o.y += base; o.z += base; o.w += base;
        ((int4*)off)[i4] = o;
        ((int4*)cur)[i4] = o;
    }
    if (b == 0 && t == 0) off[N_NODES] = N_EDGES;
}

// CSR build step 3: bucket (col, val) by row, packed int2{col, val_bits}
__global__ __launch_bounds__(256) void bucket_kernel(
    const int* __restrict__ rows, const int* __restrict__ cols, const float* __restrict__ vals,
    int* __restrict__ cur, int2* __restrict__ epack)
{
    int e = blockIdx.x * 256 + threadIdx.x;
    if (e >= N_EDGES) return;
    int r = rows[e];
    int slot = atomicAdd(&cur[r], 1);
    int2 p;
    p.x = cols[e];
    p.y = __float_as_int(vals[e]);
    epack[slot] = p;
}

// K_A (fused): y[n] = bf16( (UT[user[n]] + IT[item[n]] + BT[behavior[n]]) @ W^T )
// Swapped-operand MFMA (verified R3/R5): E[i][j] = sum_k W[i][k]*x[r0+j][k];
// C/D layout: j = lane&15 (out row), i = 16*ti + 4*(lane>>4) + q.
// v2: 512 threads (8 waves, 128 rows/block); W staged in TWO 16KB ti-halves
// (bfrag regs reused across halves) -> LDS 16KB for higher occupancy;
// staging writes are ushort4 (ds_write_b64) -> no scalar-u16 bank conflicts.
__global__ __launch_bounds__(512, 6) void fused_embed_gemm_kernel(
    const int* __restrict__ user, const int* __restrict__ item, const int* __restrict__ behavior,
    const float* __restrict__ ut, const float* __restrict__ itb, const float* __restrict__ bt,
    const float* __restrict__ W, unsigned short* __restrict__ y)
{
    __shared__ unsigned short wlds[64 * 128];   // 16 KB: 16 fragment slots

    int tid = threadIdx.x;
    int l = tid & 63;
    int w = tid >> 6;           // wave 0..7
    int c = l & 15;
    int g = l >> 4;
    int row = blockIdx.x * 128 + w * 16 + c;
    int rowc = row < N_NODES ? row : N_NODES - 1;

    int u  = user[rowc];
    int iv = item[rowc];
    int bh = behavior[rowc];
    const float4* ut4 = (const float4*)ut;
    const float4* it4 = (const float4*)itb;
    const float4* bt4 = (const float4*)bt;

    // B fragments: x[row][8g + 32s .. +7] summed from 3 tables
    bf16x8 bfrag[4];
    #pragma unroll
    for (int s = 0; s < 4; ++s) {
        int base = 8 * s + 2 * g;
        float4 a0 = ut4[(size_t)u  * 32 + base];
        float4 a1 = ut4[(size_t)u  * 32 + base + 1];
        float4 c0 = it4[(size_t)iv * 32 + base];
        float4 c1 = it4[(size_t)iv * 32 + base + 1];
        float4 d0 = bt4[(size_t)bh * 32 + base];
        float4 d1 = bt4[(size_t)bh * 32 + base + 1];
        bf16x8 t;
        t[0] = (short)f2bf(a0.x + c0.x + d0.x);
        t[1] = (short)f2bf(a0.y + c0.y + d0.y);
        t[2] = (short)f2bf(a0.z + c0.z + d0.z);
        t[3] = (short)f2bf(a0.w + c0.w + d0.w);
        t[4] = (short)f2bf(a1.x + c1.x + d1.x);
        t[5] = (short)f2bf(a1.y + c1.y + d1.y);
        t[6] = (short)f2bf(a1.z + c1.z + d1.z);
        t[7] = (short)f2bf(a1.w + c1.w + d1.w);
        bfrag[s] = t;
    }

    f32x4 acc[8];
    #pragma unroll
    for (int ti = 0; ti < 8; ++ti) acc[ti] = (f32x4){0.f, 0.f, 0.f, 0.f};

    const bf16x8* wf = (const bf16x8*)wlds;   // frag index = slot*64 + lane
    #pragma unroll
    for (int half = 0; half < 2; ++half) {
        __syncthreads();   // protect previous half's reads (no-op cost at half 0)
        // stage W rows [64*half, 64*half+64) into 16 fragment slots
        for (int c4 = tid; c4 < 2048; c4 += 512) {
            float4 wv = ((const float4*)W)[half * 2048 + c4];
            int il = c4 >> 5;            // local W row 0..63 (out col local)
            int k0 = (c4 & 31) * 4;      // W col (k)
            int slot = (il >> 4) * 4 + (k0 >> 5);          // ti_local*4 + s
            int lane = ((k0 & 31) >> 3) * 16 + (il & 15);  // g*16 + c
            ushort4 o;
            o.x = f2bf(wv.x); o.y = f2bf(wv.y); o.z = f2bf(wv.z); o.w = f2bf(wv.w);
            *(ushort4*)&wlds[slot * 512 + lane * 8 + (k0 & 7)] = o;
        }
        __syncthreads();
        #pragma unroll
        for (int tl = 0; tl < 4; ++tl) {
            #pragma unroll
            for (int s = 0; s < 4; ++s) {
                bf16x8 af = wf[(tl * 4 + s) * 64 + l];
                acc[half * 4 + tl] =
                    __builtin_amdgcn_mfma_f32_16x16x32_bf16(af, bfrag[s], acc[half * 4 + tl], 0, 0, 0);
            }
        }
    }

    if (row < N_NODES) {
        unsigned short* yr = y + (size_t)row * DIM;
        #pragma unroll
        for (int ti = 0; ti < 8; ++ti) {
            ushort4 o;
            o.x = f2bf(acc[ti][0]);
            o.y = f2bf(acc[ti][1]);
            o.z = f2bf(acc[ti][2]);
            o.w = f2bf(acc[ti][3]);
            *(ushort4*)(yr + 16 * ti + 4 * g) = o;
        }
    }
}

// K_B: out[r] = b + sum_{e in row r} val[e] * y[col[e]]   (y bf16, acc f32)
// 16 lanes per row, each lane covers 8 consecutive cols (16B gather per edge)
__global__ __launch_bounds__(256) void agg_bias_kernel(
    const int* __restrict__ off, const int2* __restrict__ epack,
    const unsigned short* __restrict__ y, const float* __restrict__ bias,
    float* __restrict__ out)
{
    int gid = blockIdx.x * 256 + threadIdx.x;
    int r = gid >> 4;
    int m = gid & 15;
    if (r >= N_NODES) return;
    int s = off[r], e = off[r + 1];
    const bf16x8* y8 = (const bf16x8*)y;   // index = node*16 + m

    float a0[8], a1[8];
    #pragma unroll
    for (int j = 0; j < 8; ++j) { a0[j] = 0.f; a1[j] = 0.f; }

    int i = s;
    for (; i + 1 < e; i += 2) {
        int2 p0 = epack[i];
        int2 p1 = epack[i + 1];
        float v0 = __int_as_float(p0.y);
        float v1 = __int_as_float(p1.y);
        bf16x8 ya = y8[(size_t)p0.x * 16 + m];
        bf16x8 yb = y8[(size_t)p1.x * 16 + m];
        #pragma unroll
        for (int j = 0; j < 8; ++j) {
            a0[j] = fmaf(v0, bf2f((unsigned short)ya[j]), a0[j]);
            a1[j] = fmaf(v1, bf2f((unsigned short)yb[j]), a1[j]);
        }
    }
    if (i < e) {
        int2 p0 = epack[i];
        float v0 = __int_as_float(p0.y);
        bf16x8 ya = y8[(size_t)p0.x * 16 + m];
        #pragma unroll
        for (int j = 0; j < 8; ++j)
            a0[j] = fmaf(v0, bf2f((unsigned short)ya[j]), a0[j]);
    }

    const float4* b4 = (const float4*)bias;
    float4 bb0 = b4[2 * m], bb1 = b4[2 * m + 1];
    float4 o0, o1;
    o0.x = a0[0] + a1[0] + bb0.x;
    o0.y = a0[1] + a1[1] + bb0.y;
    o0.z = a0[2] + a1[2] + bb0.z;
    o0.w = a0[3] + a1[3] + bb0.w;
    o1.x = a0[4] + a1[4] + bb1.x;
    o1.y = a0[5] + a1[5] + bb1.y;
    o1.z = a0[6] + a1[6] + bb1.z;
    o1.w = a0[7] + a1[7] + bb1.w;
    float4* orow = (float4*)(out + (size_t)r * DIM);
    orow[2 * m]     = o0;
    orow[2 * m + 1] = o1;
}

// ---- fallback path kernels (mid / tiny ws) ----

__global__ __launch_bounds__(256) void agg_fused_kernel(
    const int* __restrict__ off, const int2* __restrict__ epack,
    const int* __restrict__ user, const int* __restrict__ item, const int* __restrict__ behavior,
    const float* __restrict__ ut, const float* __restrict__ itb, const float* __restrict__ bt,
    float* __restrict__ out)
{
    int gid = blockIdx.x * 256 + threadIdx.x;
    int r = gid >> 5;
    int m = gid & 31;
    if (r >= N_NODES) return;
    int s = off[r], e = off[r + 1];
    const float4* ut4 = (const float4*)ut;
    const float4* it4 = (const float4*)itb;
    const float4* bt4 = (const float4*)bt;
    float4 acc = {0.f, 0.f, 0.f, 0.f};
    for (int i = s; i < e; ++i) {
        int2 p = epack[i];
        int c = p.x;
        float v = __int_as_float(p.y);
        float4 a = ut4[(size_t)user[c] * 32 + m];
        float4 cc = it4[(size_t)item[c] * 32 + m];
        float4 d = bt4[(size_t)behavior[c] * 32 + m];
        a.x += cc.x + d.x; a.y += cc.y + d.y; a.z += cc.z + d.z; a.w += cc.w + d.w;
        fma4(acc, v, a);
    }
    ((float4*)out)[(size_t)r * 32 + m] = acc;
}

__global__ __launch_bounds__(256) void scatter_fused_kernel(
    const int* __restrict__ rows, const int* __restrict__ cols, const float* __restrict__ vals,
    const int* __restrict__ user, const int* __restrict__ item, const int* __restrict__ behavior,
    const float* __restrict__ ut, const float* __restrict__ itb, const float* __restrict__ bt,
    float* __restrict__ agg)
{
    int wave = (blockIdx.x * 256 + threadIdx.x) >> 6;
    int lane = threadIdx.x & 63;
    int e = wave * 2 + (lane >> 5);
    if (e >= N_EDGES) return;
    int r = rows[e];
    int c = cols[e];
    float v = vals[e];
    int m = lane & 31;
    const float4* ut4 = (const float4*)ut;
    const float4* it4 = (const float4*)itb;
    const float4* bt4 = (const float4*)bt;
    float4 a = ut4[(size_t)user[c] * 32 + m];
    float4 cc = it4[(size_t)item[c] * 32 + m];
    float4 d = bt4[(size_t)behavior[c] * 32 + m];
    a.x += cc.x + d.x; a.y += cc.y + d.y; a.z += cc.z + d.z; a.w += cc.w + d.w;
    float* o = agg + (size_t)r * DIM + m * 4;
    atomicAdd(o + 0, v * a.x);
    atomicAdd(o + 1, v * a.y);
    atomicAdd(o + 2, v * a.z);
    atomicAdd(o + 3, v * a.w);
}

// fallback GEMM: out[r] = agg[r] @ W^T + b, in-place on io (verified R3 structure)
__global__ __launch_bounds__(256) void gemm_mfma_kernel(
    const float* __restrict__ W, const float* __restrict__ bias, float* io)
{
    __shared__ unsigned short wlds[128 * 128];

    int tid = threadIdx.x;
    for (int c4 = tid; c4 < 128 * 128 / 4; c4 += 256) {
        float4 wv = ((const float4*)W)[c4];
        int i  = c4 >> 5;
        int k0 = (c4 & 31) * 4;
        int slot = (i >> 4) * 4 + (k0 >> 5);
        int lane = ((k0 & 31) >> 3) * 16 + (i & 15);
        ushort4 o;
        o.x = f2bf(wv.x); o.y = f2bf(wv.y); o.z = f2bf(wv.z); o.w = f2bf(wv.w);
        *(ushort4*)&wlds[slot * 512 + lane * 8 + (k0 & 7)] = o;
    }
    __syncthreads();

    int l = tid & 63;
    int w = tid >> 6;
    int c = l & 15;
    int g = l >> 4;
    int r0 = blockIdx.x * 64 + w * 16;
    int row = r0 + c;
    int rowc = row < N_NODES ? row : N_NODES - 1;

    const float4* a4 = (const float4*)io;
    bf16x8 bfrag[4];
    #pragma unroll
    for (int s = 0; s < 4; ++s) {
        float4 p0 = a4[(size_t)rowc * 32 + 8 * s + 2 * g];
        float4 p1 = a4[(size_t)rowc * 32 + 8 * s + 2 * g + 1];
        bf16x8 t;
        t[0] = (short)f2bf(p0.x); t[1] = (short)f2bf(p0.y);
        t[2] = (short)f2bf(p0.z); t[3] = (short)f2bf(p0.w);
        t[4] = (short)f2bf(p1.x); t[5] = (short)f2bf(p1.y);
        t[6] = (short)f2bf(p1.z); t[7] = (short)f2bf(p1.w);
        bfrag[s] = t;
    }

    f32x4 acc[8];
    #pragma unroll
    for (int ti = 0; ti < 8; ++ti) acc[ti] = (f32x4){0.f, 0.f, 0.f, 0.f};

    const bf16x8* wf = (const bf16x8*)wlds;
    #pragma unroll
    for (int ti = 0; ti < 8; ++ti) {
        #pragma unroll
        for (int s = 0; s < 4; ++s) {
            bf16x8 af = wf[(ti * 4 + s) * 64 + l];
            acc[ti] = __builtin_amdgcn_mfma_f32_16x16x32_bf16(af, bfrag[s], acc[ti], 0, 0, 0);
        }
    }

    if (row < N_NODES) {
        float4* orow = (float4*)(io + (size_t)row * DIM);
        const float4* b4 = (const float4*)bias;
        #pragma unroll
        for (int ti = 0; ti < 8; ++ti) {
            float4 bb = b4[ti * 4 + g];
            float4 o;
            o.x = acc[ti][0] + bb.x;
            o.y = acc[ti][1] + bb.y;
            o.z = acc[ti][2] + bb.z;
            o.w = acc[ti][3] + bb.w;
            orow[ti * 4 + g] = o;
        }
    }
}

extern "C" void kernel_launch(void* const* d_in, const int* in_sizes, int n_in,
                              void* d_out, int out_size, void* d_ws, size_t ws_size,
                              hipStream_t stream) {
    const int*   user           = (const int*)d_in[0];
    const int*   item           = (const int*)d_in[1];
    const int*   behavior       = (const int*)d_in[2];
    const int*   adj_rows       = (const int*)d_in[3];
    const int*   adj_cols       = (const int*)d_in[4];
    const float* adj_vals       = (const float*)d_in[5];
    const float* user_table     = (const float*)d_in[6];
    const float* item_table     = (const float*)d_in[7];
    const float* behavior_table = (const float*)d_in[8];
    const float* W              = (const float*)d_in[9];
    const float* b              = (const float*)d_in[10];
    float* out = (float*)d_out;

    const size_t Y_BYTES    = (size_t)N_NODES * DIM * sizeof(unsigned short); // 25,600,000
    const size_t CNT_BYTES  = (size_t)N_NODES * sizeof(int);                  // 400,000
    const size_t OFF_BYTES  = ((size_t)(N_NODES + 1) * sizeof(int) + 15) & ~(size_t)15;
    const size_t EPACK_BYTES = (size_t)N_EDGES * sizeof(int2);                // 4,800,000

    const int edge_blocks = (N_EDGES + 255) / 256;
    const int fused_blocks = (N_NODES + 127) / 128;   // 782
    const int gemm_blocks = (N_NODES + 63) / 64;      // 1563 (fallback)
    const int agg_blocks  = (N_NODES * 16 + 255) / 256;  // 6250

    char* ws = (char*)d_ws;
    const size_t need_full = Y_BYTES + CNT_BYTES + OFF_BYTES + EPACK_BYTES;
    const size_t need_csr  = CNT_BYTES + OFF_BYTES + EPACK_BYTES;

    if (ws_size >= need_full) {
        unsigned short* y = (unsigned short*)ws;
        int*  cnt   = (int*)(ws + Y_BYTES);
        int*  off   = (int*)(ws + Y_BYTES + CNT_BYTES);
        int2* epack = (int2*)(ws + Y_BYTES + CNT_BYTES + OFF_BYTES);
        int*  bsum  = (int*)epack;   // epack[0..48] dead until bucket; stream-ordered

        hipMemsetAsync(cnt, 0, CNT_BYTES, stream);
        hist_kernel<<<edge_blocks, 256, 0, stream>>>(adj_rows, cnt);
        scan1_kernel<<<SCAN_BLOCKS, 256, 0, stream>>>(cnt, off, bsum);
        scan3_kernel<<<SCAN_BLOCKS, 256, 0, stream>>>(bsum, off, cnt);
        bucket_kernel<<<edge_blocks, 256, 0, stream>>>(
            adj_rows, adj_cols, adj_vals, cnt, epack);
        fused_embed_gemm_kernel<<<fused_blocks, 512, 0, stream>>>(
            user, item, behavior, user_table, item_table, behavior_table, W, y);
        agg_bias_kernel<<<agg_blocks, 256, 0, stream>>>(off, epack, y, b, out);
    } else if (ws_size >= need_csr) {
        int*  cnt   = (int*)ws;
        int*  off   = (int*)(ws + CNT_BYTES);
        int2* epack = (int2*)(ws + CNT_BYTES + OFF_BYTES);
        int*  bsum  = (int*)epack;

        hipMemsetAsync(cnt, 0, CNT_BYTES, stream);
        hist_kernel<<<edge_blocks, 256, 0, stream>>>(adj_rows, cnt);
        scan1_kernel<<<SCAN_BLOCKS, 256, 0, stream>>>(cnt, off, bsum);
        scan3_kernel<<<SCAN_BLOCKS, 256, 0, stream>>>(bsum, off, cnt);
        bucket_kernel<<<edge_blocks, 256, 0, stream>>>(
            adj_rows, adj_cols, adj_vals, cnt, epack);
        agg_fused_kernel<<<(N_NODES * 32 + 255) / 256, 256, 0, stream>>>(
            off, epack, user, item, behavior,
            user_table, item_table, behavior_table, out);
        gemm_mfma_kernel<<<gemm_blocks, 256, 0, stream>>>(W, b, out);
    } else {
        hipMemsetAsync(d_out, 0, (size_t)N_NODES * DIM * sizeof(float), stream);
        const int scatter_blocks = (N_EDGES / 2 * 64 + 255) / 256;
        scatter_fused_kernel<<<scatter_blocks, 256, 0, stream>>>(
            adj_rows, adj_cols, adj_vals, user, item, behavior,
            user_table, item_table, behavior_table, out);
        gemm_mfma_kernel<<<gemm_blocks, 256, 0, stream>>>(W, b, out);
    }
}

// Round 7
// 146.713 us; speedup vs baseline: 1.1127x; 1.1127x over previous
//
#include <hip/hip_runtime.h>

#define N_NODES 100000
#define N_EDGES 600000
#define DIM 128

#define N4 (N_NODES / 4)          // 25000 int4 chunks of the count array
#define SCAN_BLOCKS ((N_NODES + 1023) / 1024)   // 98

typedef __attribute__((ext_vector_type(8))) short bf16x8;
typedef __attribute__((ext_vector_type(4))) float f32x4;

__device__ __forceinline__ void fma4(float4& acc, float s, const float4 w) {
    acc.x = fmaf(s, w.x, acc.x);
    acc.y = fmaf(s, w.y, acc.y);
    acc.z = fmaf(s, w.z, acc.z);
    acc.w = fmaf(s, w.w, acc.w);
}

__device__ __forceinline__ unsigned short f2bf(float f) {
    union { float f; unsigned int u; } v; v.f = f;
    unsigned int r = v.u + 0x7fffu + ((v.u >> 16) & 1u);   // RNE
    return (unsigned short)(r >> 16);
}

__device__ __forceinline__ float bf2f(unsigned short u) {
    union { unsigned int i; float f; } v;
    v.i = ((unsigned int)u) << 16;
    return v.f;
}

// CSR build step 1: degree histogram (cnt must be zeroed before)
__global__ __launch_bounds__(256) void hist_kernel(
    const int* __restrict__ rows, int* __restrict__ cnt)
{
    int e = blockIdx.x * 256 + threadIdx.x;
    if (e >= N_EDGES) return;
    atomicAdd(&cnt[rows[e]], 1);
}

// scan level 1
__global__ __launch_bounds__(256) void scan1_kernel(
    const int* __restrict__ cnt, int* __restrict__ off, int* __restrict__ bsum)
{
    __shared__ int s[256];
    int t = threadIdx.x;
    int b = blockIdx.x;
    int i4 = b * 256 + t;
    int4 c = {0, 0, 0, 0};
    if (i4 < N4) c = ((const int4*)cnt)[i4];
    int tsum = c.x + c.y + c.z + c.w;
    s[t] = tsum;
    __syncthreads();
    for (int d = 1; d < 256; d <<= 1) {
        int v = (t >= d) ? s[t - d] : 0;
        __syncthreads();
        s[t] += v;
        __syncthreads();
    }
    int texcl = s[t] - tsum;
    if (t == 255) bsum[b] = s[255];
    if (i4 < N4) {
        int4 o;
        o.x = texcl;
        o.y = o.x + c.x;
        o.z = o.y + c.y;
        o.w = o.z + c.z;
        ((int4*)off)[i4] = o;
    }
}

// scan level 2+3
__global__ __launch_bounds__(256) void scan3_kernel(
    const int* __restrict__ bsum, int* __restrict__ off, int* __restrict__ cur)
{
    __shared__ int s[256];
    int t = threadIdx.x;
    int b = blockIdx.x;
    s[t] = (t < b && t < SCAN_BLOCKS) ? bsum[t] : 0;
    __syncthreads();
    for (int d = 1; d < 256; d <<= 1) {
        int v = (t >= d) ? s[t - d] : 0;
        __syncthreads();
        s[t] += v;
        __syncthreads();
    }
    int base = s[255];
    int i4 = b * 256 + t;
    if (i4 < N4) {
        int4 o = ((const int4*)off)[i4];
        o.x += base; o.y += base; o.z += base; o.w += base;
        ((int4*)off)[i4] = o;
        ((int4*)cur)[i4] = o;
    }
    if (b == 0 && t == 0) off[N_NODES] = N_EDGES;
}

// CSR build step 3: bucket (col, val) by row, packed int2{col, val_bits}
__global__ __launch_bounds__(256) void bucket_kernel(
    const int* __restrict__ rows, const int* __restrict__ cols, const float* __restrict__ vals,
    int* __restrict__ cur, int2* __restrict__ epack)
{
    int e = blockIdx.x * 256 + threadIdx.x;
    if (e >= N_EDGES) return;
    int r = rows[e];
    int slot = atomicAdd(&cur[r], 1);
    int2 p;
    p.x = cols[e];
    p.y = __float_as_int(vals[e]);
    epack[slot] = p;
}

// W pre-conversion: f32 row-major [i][k] -> bf16 fragment-ordered wfrag.
// Fragment layout (verified R3-R5): slot = (i>>4)*4 + (k0>>5); within slot,
// lane = ((k0&31)>>3)*16 + (i&15); element u = k0&7. bf16x8 per lane per slot.
__global__ __launch_bounds__(256) void wconv_kernel(
    const float* __restrict__ W, unsigned short* __restrict__ wfrag)
{
    int c4 = blockIdx.x * 256 + threadIdx.x;
    if (c4 >= 128 * 128 / 4) return;
    float4 wv = ((const float4*)W)[c4];
    int i  = c4 >> 5;            // W row (out col)
    int k0 = (c4 & 31) * 4;      // W col (k)
    int slot = (i >> 4) * 4 + (k0 >> 5);
    int lane = ((k0 & 31) >> 3) * 16 + (i & 15);
    ushort4 o;
    o.x = f2bf(wv.x); o.y = f2bf(wv.y); o.z = f2bf(wv.z); o.w = f2bf(wv.w);
    *(ushort4*)&wfrag[slot * 512 + lane * 8 + (k0 & 7)] = o;
}

// K_A (fused): y[n] = bf16( (UT[user[n]] + IT[item[n]] + BT[behavior[n]]) @ W^T )
// v3: NO LDS, NO barriers — waves fully independent. W fragments read from
// the pre-converted global wfrag (1KB coalesced per slot, identical across
// waves -> L1-resident). Occupancy VGPR-bound only.
// Swapped-operand MFMA: E[i][j] = sum_k W[i][k]*x[r0+j][k];
// C/D layout: j = lane&15 (out row), i = 16*ti + 4*(lane>>4) + q.
__global__ __launch_bounds__(256, 6) void fused_embed_gemm_kernel(
    const int* __restrict__ user, const int* __restrict__ item, const int* __restrict__ behavior,
    const float* __restrict__ ut, const float* __restrict__ itb, const float* __restrict__ bt,
    const bf16x8* __restrict__ wf, unsigned short* __restrict__ y)
{
    int tid = threadIdx.x;
    int l = tid & 63;
    int w = tid >> 6;           // wave 0..3
    int c = l & 15;
    int g = l >> 4;
    int row = blockIdx.x * 64 + w * 16 + c;
    int rowc = row < N_NODES ? row : N_NODES - 1;

    int u  = user[rowc];
    int iv = item[rowc];
    int bh = behavior[rowc];
    const float4* ut4 = (const float4*)ut;
    const float4* it4 = (const float4*)itb;
    const float4* bt4 = (const float4*)bt;

    // B fragments: x[row][8g + 32s .. +7] summed from 3 tables
    bf16x8 bfrag[4];
    #pragma unroll
    for (int s = 0; s < 4; ++s) {
        int base = 8 * s + 2 * g;
        float4 a0 = ut4[(size_t)u  * 32 + base];
        float4 a1 = ut4[(size_t)u  * 32 + base + 1];
        float4 c0 = it4[(size_t)iv * 32 + base];
        float4 c1 = it4[(size_t)iv * 32 + base + 1];
        float4 d0 = bt4[(size_t)bh * 32 + base];
        float4 d1 = bt4[(size_t)bh * 32 + base + 1];
        bf16x8 t;
        t[0] = (short)f2bf(a0.x + c0.x + d0.x);
        t[1] = (short)f2bf(a0.y + c0.y + d0.y);
        t[2] = (short)f2bf(a0.z + c0.z + d0.z);
        t[3] = (short)f2bf(a0.w + c0.w + d0.w);
        t[4] = (short)f2bf(a1.x + c1.x + d1.x);
        t[5] = (short)f2bf(a1.y + c1.y + d1.y);
        t[6] = (short)f2bf(a1.z + c1.z + d1.z);
        t[7] = (short)f2bf(a1.w + c1.w + d1.w);
        bfrag[s] = t;
    }

    f32x4 acc[8];
    #pragma unroll
    for (int ti = 0; ti < 8; ++ti) acc[ti] = (f32x4){0.f, 0.f, 0.f, 0.f};

    #pragma unroll
    for (int ti = 0; ti < 8; ++ti) {
        #pragma unroll
        for (int s = 0; s < 4; ++s) {
            bf16x8 af = wf[(ti * 4 + s) * 64 + l];
            acc[ti] = __builtin_amdgcn_mfma_f32_16x16x32_bf16(af, bfrag[s], acc[ti], 0, 0, 0);
        }
    }

    if (row < N_NODES) {
        unsigned short* yr = y + (size_t)row * DIM;
        #pragma unroll
        for (int ti = 0; ti < 8; ++ti) {
            ushort4 o;
            o.x = f2bf(acc[ti][0]);
            o.y = f2bf(acc[ti][1]);
            o.z = f2bf(acc[ti][2]);
            o.w = f2bf(acc[ti][3]);
            *(ushort4*)(yr + 16 * ti + 4 * g) = o;
        }
    }
}

// K_B: out[r] = b + sum_{e in row r} val[e] * y[col[e]]   (y bf16, acc f32)
// 16 lanes per row, each lane covers 8 consecutive cols (16B gather per edge)
__global__ __launch_bounds__(256) void agg_bias_kernel(
    const int* __restrict__ off, const int2* __restrict__ epack,
    const unsigned short* __restrict__ y, const float* __restrict__ bias,
    float* __restrict__ out)
{
    int gid = blockIdx.x * 256 + threadIdx.x;
    int r = gid >> 4;
    int m = gid & 15;
    if (r >= N_NODES) return;
    int s = off[r], e = off[r + 1];
    const bf16x8* y8 = (const bf16x8*)y;   // index = node*16 + m

    float a0[8], a1[8];
    #pragma unroll
    for (int j = 0; j < 8; ++j) { a0[j] = 0.f; a1[j] = 0.f; }

    int i = s;
    for (; i + 1 < e; i += 2) {
        int2 p0 = epack[i];
        int2 p1 = epack[i + 1];
        float v0 = __int_as_float(p0.y);
        float v1 = __int_as_float(p1.y);
        bf16x8 ya = y8[(size_t)p0.x * 16 + m];
        bf16x8 yb = y8[(size_t)p1.x * 16 + m];
        #pragma unroll
        for (int j = 0; j < 8; ++j) {
            a0[j] = fmaf(v0, bf2f((unsigned short)ya[j]), a0[j]);
            a1[j] = fmaf(v1, bf2f((unsigned short)yb[j]), a1[j]);
        }
    }
    if (i < e) {
        int2 p0 = epack[i];
        float v0 = __int_as_float(p0.y);
        bf16x8 ya = y8[(size_t)p0.x * 16 + m];
        #pragma unroll
        for (int j = 0; j < 8; ++j)
            a0[j] = fmaf(v0, bf2f((unsigned short)ya[j]), a0[j]);
    }

    const float4* b4 = (const float4*)bias;
    float4 bb0 = b4[2 * m], bb1 = b4[2 * m + 1];
    float4 o0, o1;
    o0.x = a0[0] + a1[0] + bb0.x;
    o0.y = a0[1] + a1[1] + bb0.y;
    o0.z = a0[2] + a1[2] + bb0.z;
    o0.w = a0[3] + a1[3] + bb0.w;
    o1.x = a0[4] + a1[4] + bb1.x;
    o1.y = a0[5] + a1[5] + bb1.y;
    o1.z = a0[6] + a1[6] + bb1.z;
    o1.w = a0[7] + a1[7] + bb1.w;
    float4* orow = (float4*)(out + (size_t)r * DIM);
    orow[2 * m]     = o0;
    orow[2 * m + 1] = o1;
}

// ---- fallback path kernels (mid / tiny ws) ----

__global__ __launch_bounds__(256) void agg_fused_kernel(
    const int* __restrict__ off, const int2* __restrict__ epack,
    const int* __restrict__ user, const int* __restrict__ item, const int* __restrict__ behavior,
    const float* __restrict__ ut, const float* __restrict__ itb, const float* __restrict__ bt,
    float* __restrict__ out)
{
    int gid = blockIdx.x * 256 + threadIdx.x;
    int r = gid >> 5;
    int m = gid & 31;
    if (r >= N_NODES) return;
    int s = off[r], e = off[r + 1];
    const float4* ut4 = (const float4*)ut;
    const float4* it4 = (const float4*)itb;
    const float4* bt4 = (const float4*)bt;
    float4 acc = {0.f, 0.f, 0.f, 0.f};
    for (int i = s; i < e; ++i) {
        int2 p = epack[i];
        int c = p.x;
        float v = __int_as_float(p.y);
        float4 a = ut4[(size_t)user[c] * 32 + m];
        float4 cc = it4[(size_t)item[c] * 32 + m];
        float4 d = bt4[(size_t)behavior[c] * 32 + m];
        a.x += cc.x + d.x; a.y += cc.y + d.y; a.z += cc.z + d.z; a.w += cc.w + d.w;
        fma4(acc, v, a);
    }
    ((float4*)out)[(size_t)r * 32 + m] = acc;
}

__global__ __launch_bounds__(256) void scatter_fused_kernel(
    const int* __restrict__ rows, const int* __restrict__ cols, const float* __restrict__ vals,
    const int* __restrict__ user, const int* __restrict__ item, const int* __restrict__ behavior,
    const float* __restrict__ ut, const float* __restrict__ itb, const float* __restrict__ bt,
    float* __restrict__ agg)
{
    int wave = (blockIdx.x * 256 + threadIdx.x) >> 6;
    int lane = threadIdx.x & 63;
    int e = wave * 2 + (lane >> 5);
    if (e >= N_EDGES) return;
    int r = rows[e];
    int c = cols[e];
    float v = vals[e];
    int m = lane & 31;
    const float4* ut4 = (const float4*)ut;
    const float4* it4 = (const float4*)itb;
    const float4* bt4 = (const float4*)bt;
    float4 a = ut4[(size_t)user[c] * 32 + m];
    float4 cc = it4[(size_t)item[c] * 32 + m];
    float4 d = bt4[(size_t)behavior[c] * 32 + m];
    a.x += cc.x + d.x; a.y += cc.y + d.y; a.z += cc.z + d.z; a.w += cc.w + d.w;
    float* o = agg + (size_t)r * DIM + m * 4;
    atomicAdd(o + 0, v * a.x);
    atomicAdd(o + 1, v * a.y);
    atomicAdd(o + 2, v * a.z);
    atomicAdd(o + 3, v * a.w);
}

// fallback GEMM: out[r] = agg[r] @ W^T + b, in-place on io (verified R3 structure)
__global__ __launch_bounds__(256) void gemm_mfma_kernel(
    const float* __restrict__ W, const float* __restrict__ bias, float* io)
{
    __shared__ unsigned short wlds[128 * 128];

    int tid = threadIdx.x;
    for (int c4 = tid; c4 < 128 * 128 / 4; c4 += 256) {
        float4 wv = ((const float4*)W)[c4];
        int i  = c4 >> 5;
        int k0 = (c4 & 31) * 4;
        int slot = (i >> 4) * 4 + (k0 >> 5);
        int lane = ((k0 & 31) >> 3) * 16 + (i & 15);
        ushort4 o;
        o.x = f2bf(wv.x); o.y = f2bf(wv.y); o.z = f2bf(wv.z); o.w = f2bf(wv.w);
        *(ushort4*)&wlds[slot * 512 + lane * 8 + (k0 & 7)] = o;
    }
    __syncthreads();

    int l = tid & 63;
    int w = tid >> 6;
    int c = l & 15;
    int g = l >> 4;
    int r0 = blockIdx.x * 64 + w * 16;
    int row = r0 + c;
    int rowc = row < N_NODES ? row : N_NODES - 1;

    const float4* a4 = (const float4*)io;
    bf16x8 bfrag[4];
    #pragma unroll
    for (int s = 0; s < 4; ++s) {
        float4 p0 = a4[(size_t)rowc * 32 + 8 * s + 2 * g];
        float4 p1 = a4[(size_t)rowc * 32 + 8 * s + 2 * g + 1];
        bf16x8 t;
        t[0] = (short)f2bf(p0.x); t[1] = (short)f2bf(p0.y);
        t[2] = (short)f2bf(p0.z); t[3] = (short)f2bf(p0.w);
        t[4] = (short)f2bf(p1.x); t[5] = (short)f2bf(p1.y);
        t[6] = (short)f2bf(p1.z); t[7] = (short)f2bf(p1.w);
        bfrag[s] = t;
    }

    f32x4 acc[8];
    #pragma unroll
    for (int ti = 0; ti < 8; ++ti) acc[ti] = (f32x4){0.f, 0.f, 0.f, 0.f};

    const bf16x8* wf = (const bf16x8*)wlds;
    #pragma unroll
    for (int ti = 0; ti < 8; ++ti) {
        #pragma unroll
        for (int s = 0; s < 4; ++s) {
            bf16x8 af = wf[(ti * 4 + s) * 64 + l];
            acc[ti] = __builtin_amdgcn_mfma_f32_16x16x32_bf16(af, bfrag[s], acc[ti], 0, 0, 0);
        }
    }

    if (row < N_NODES) {
        float4* orow = (float4*)(io + (size_t)row * DIM);
        const float4* b4 = (const float4*)bias;
        #pragma unroll
        for (int ti = 0; ti < 8; ++ti) {
            float4 bb = b4[ti * 4 + g];
            float4 o;
            o.x = acc[ti][0] + bb.x;
            o.y = acc[ti][1] + bb.y;
            o.z = acc[ti][2] + bb.z;
            o.w = acc[ti][3] + bb.w;
            orow[ti * 4 + g] = o;
        }
    }
}

extern "C" void kernel_launch(void* const* d_in, const int* in_sizes, int n_in,
                              void* d_out, int out_size, void* d_ws, size_t ws_size,
                              hipStream_t stream) {
    const int*   user           = (const int*)d_in[0];
    const int*   item           = (const int*)d_in[1];
    const int*   behavior       = (const int*)d_in[2];
    const int*   adj_rows       = (const int*)d_in[3];
    const int*   adj_cols       = (const int*)d_in[4];
    const float* adj_vals       = (const float*)d_in[5];
    const float* user_table     = (const float*)d_in[6];
    const float* item_table     = (const float*)d_in[7];
    const float* behavior_table = (const float*)d_in[8];
    const float* W              = (const float*)d_in[9];
    const float* b              = (const float*)d_in[10];
    float* out = (float*)d_out;

    const size_t Y_BYTES     = (size_t)N_NODES * DIM * sizeof(unsigned short); // 25,600,000
    const size_t CNT_BYTES   = (size_t)N_NODES * sizeof(int);                  // 400,000
    const size_t OFF_BYTES   = ((size_t)(N_NODES + 1) * sizeof(int) + 15) & ~(size_t)15;
    const size_t EPACK_BYTES = (size_t)N_EDGES * sizeof(int2);                 // 4,800,000
    const size_t WFRAG_BYTES = 128 * 128 * sizeof(unsigned short);             // 32,768

    const int edge_blocks = (N_EDGES + 255) / 256;
    const int fused_blocks = (N_NODES + 63) / 64;        // 1563
    const int gemm_blocks = (N_NODES + 63) / 64;         // 1563 (fallback)
    const int agg_blocks  = (N_NODES * 16 + 255) / 256;  // 6250

    char* ws = (char*)d_ws;
    const size_t need_full = Y_BYTES + CNT_BYTES + OFF_BYTES + EPACK_BYTES + WFRAG_BYTES;
    const size_t need_csr  = CNT_BYTES + OFF_BYTES + EPACK_BYTES;

    if (ws_size >= need_full) {
        unsigned short* y = (unsigned short*)ws;
        int*  cnt   = (int*)(ws + Y_BYTES);
        int*  off   = (int*)(ws + Y_BYTES + CNT_BYTES);
        int2* epack = (int2*)(ws + Y_BYTES + CNT_BYTES + OFF_BYTES);
        unsigned short* wfrag = (unsigned short*)(ws + Y_BYTES + CNT_BYTES + OFF_BYTES + EPACK_BYTES);
        int*  bsum  = (int*)epack;   // epack[0..97] dead until bucket; stream-ordered

        hipMemsetAsync(cnt, 0, CNT_BYTES, stream);
        wconv_kernel<<<16, 256, 0, stream>>>(W, wfrag);
        hist_kernel<<<edge_blocks, 256, 0, stream>>>(adj_rows, cnt);
        scan1_kernel<<<SCAN_BLOCKS, 256, 0, stream>>>(cnt, off, bsum);
        scan3_kernel<<<SCAN_BLOCKS, 256, 0, stream>>>(bsum, off, cnt);
        bucket_kernel<<<edge_blocks, 256, 0, stream>>>(
            adj_rows, adj_cols, adj_vals, cnt, epack);
        fused_embed_gemm_kernel<<<fused_blocks, 256, 0, stream>>>(
            user, item, behavior, user_table, item_table, behavior_table,
            (const bf16x8*)wfrag, y);
        agg_bias_kernel<<<agg_blocks, 256, 0, stream>>>(off, epack, y, b, out);
    } else if (ws_size >= need_csr) {
        int*  cnt   = (int*)ws;
        int*  off   = (int*)(ws + CNT_BYTES);
        int2* epack = (int2*)(ws + CNT_BYTES + OFF_BYTES);
        int*  bsum  = (int*)epack;

        hipMemsetAsync(cnt, 0, CNT_BYTES, stream);
        hist_kernel<<<edge_blocks, 256, 0, stream>>>(adj_rows, cnt);
        scan1_kernel<<<SCAN_BLOCKS, 256, 0, stream>>>(cnt, off, bsum);
        scan3_kernel<<<SCAN_BLOCKS, 256, 0, stream>>>(bsum, off, cnt);
        bucket_kernel<<<edge_blocks, 256, 0, stream>>>(
            adj_rows, adj_cols, adj_vals, cnt, epack);
        agg_fused_kernel<<<(N_NODES * 32 + 255) / 256, 256, 0, stream>>>(
            off, epack, user, item, behavior,
            user_table, item_table, behavior_table, out);
        gemm_mfma_kernel<<<gemm_blocks, 256, 0, stream>>>(W, b, out);
    } else {
        hipMemsetAsync(d_out, 0, (size_t)N_NODES * DIM * sizeof(float), stream);
        const int scatter_blocks = (N_EDGES / 2 * 64 + 255) / 256;
        scatter_fused_kernel<<<scatter_blocks, 256, 0, stream>>>(
            adj_rows, adj_cols, adj_vals, user, item, behavior,
            user_table, item_table, behavior_table, out);
        gemm_mfma_kernel<<<gemm_blocks, 256, 0, stream>>>(W, b, out);
    }
}